// Round 13
// baseline (111.569 us; speedup 1.0000x reference)
//
#include <hip/hip_runtime.h>
#include <hip/hip_bf16.h>

// Problem constants: B=2, H=1, LQ=LK=512, D=64, HID=128
// rows (B*H*L) = 1024 for q/k/v each.

#define NROWS 1024   // B*H*LQ
#define DD    64
#define HH    128
#define LK_   512
#define QR    4      // query rows per attn block

// ---------------------------------------------------------------------------
// Kernel A: projections + transposed k-table emit + Wd-folded v-projection.
// (unchanged from round 9/10)
// ---------------------------------------------------------------------------
__global__ __launch_bounds__(128)
void proj_kernel(const float* __restrict__ q, const float* __restrict__ k,
                 const float* __restrict__ v,
                 const float* __restrict__ Ww, const float* __restrict__ wb,
                 const float* __restrict__ W1, const float* __restrict__ b1,
                 const float* __restrict__ Wd,
                 float* __restrict__ vpd,
                 float* __restrict__ qa, float* __restrict__ qb,
                 float* __restrict__ kaTf, float* __restrict__ kbTf)
{
    const int r    = blockIdx.x;
    const int type = r >> 10;      // 0=q,1=k,2=v
    const int idx  = r & 1023;
    const int t    = threadIdx.x;  // 0..127

    const float* src = (type == 0) ? q : (type == 1) ? k : v;

    __shared__ float x[DD];
    __shared__ float xp[DD];

    if (t < DD) x[t] = src[idx * DD + t];
    __syncthreads();

    if (t < DD) {
        float acc = wb[t];
        #pragma unroll
        for (int c = 0; c < DD; ++c) acc = fmaf(x[c], Ww[c * DD + t], acc);
        xp[t] = acc;
    }
    __syncthreads();

    if (type == 2) {
        // vpd = xp @ Wd   (threads 0..63)
        if (t < DD) {
            float acc = 0.f;
            #pragma unroll
            for (int c = 0; c < DD; ++c) acc = fmaf(xp[c], Wd[c * DD + t], acc);
            vpd[idx * DD + t] = acc;
        }
        return;
    }

    // thread t = output column h of the HID=128 projections
    float accA = 0.f;   // xp @ W1q  (W1 rows 0..63)
    float accB = 0.f;   // xp @ W1k  (W1 rows 64..127)
    #pragma unroll
    for (int d = 0; d < DD; ++d) {
        const float xv = xp[d];
        accA = fmaf(xv, W1[d * HH + t],        accA);
        accB = fmaf(xv, W1[(DD + d) * HH + t], accB);
    }
    if (type == 0) {
        qa[idx * HH + t] = accA + b1[t];
        qb[idx * HH + t] = accB + b1[t];
    } else {
        // transposed emit: h-chunked float4 layout [b][h4][j][c]
        const int b  = idx >> 9;
        const int j  = idx & (LK_ - 1);
        const int o  = ((b * (HH / 4) + (t >> 2)) * LK_ + j) * 4 + (t & 3);
        kaTf[o] = accA;
        kbTf[o] = accB;
    }
}

// ---------------------------------------------------------------------------
// Kernel B: fused logits + softmax + PV + bias.
// grid = 256 blocks (QR=4 q-rows), block = 1024 threads (16 waves)
//   -> 16 waves/CU = 4 waves/SIMD (double the latency-hiding of r8-r10).
// Per-thread tile (2 rows, 1 j): rp = t>>9 (wave-uniform), j = t&511.
// Per h4-iter: 2 k-side dwordx4 (coalesced; rp=1 group re-reads rp=0's
//   lines ~in lockstep -> L1 hits) + 4 q-side scalar dwordx4 + 1 W2 + 48 VALU.
// ---------------------------------------------------------------------------
__global__ __launch_bounds__(1024)
void attn_kernel(const float* __restrict__ mask,
                 const float* __restrict__ vpd,
                 const float* __restrict__ qa, const float* __restrict__ qb,
                 const float4* __restrict__ kaT, const float4* __restrict__ kbT,
                 const float* __restrict__ W2, const float* __restrict__ b2,
                 const float* __restrict__ db,
                 float* __restrict__ out, float* __restrict__ attn)
{
    const int row0 = blockIdx.x * QR;   // first of 4 query rows (4 | 512)
    const int b    = row0 >> 9;
    const int t    = threadIdx.x;       // 0..1023
    const int wid  = t >> 6;            // wave 0..15
    const int lane = t & 63;
    const int rp   = t >> 9;            // 0/1 row-pair selector (wave-uniform)
    const int j    = t & (LK_ - 1);     // key column 0..511

    __shared__ float p_int[LK_ * QR];   // [j][rlocal] -> b128 broadcast in PV
    __shared__ float redm[16][2];
    __shared__ float reds[16][2];
    __shared__ float opart[16][QR][DD];

    const float4* kaTb = kaT + b * (HH / 4) * LK_;
    const float4* kbTb = kbT + b * (HH / 4) * LK_;
    const float*  qaR  = qa + (row0 + 2 * rp) * HH;   // wave-uniform -> s_load
    const float*  qbR  = qb + (row0 + 2 * rp) * HH;
    const float4* w24  = reinterpret_cast<const float4*>(W2);

    // prefetch mask early (overlaps hot loop)
    float mk[2];
    #pragma unroll
    for (int r = 0; r < 2; ++r) mk[r] = mask[(row0 + 2 * rp + r) * LK_ + j];

    // ---- logits: 2 rows x 1 col x (2 relu-dot terms over HID=128) ----
    float s1[2] = {0.f, 0.f};
    float s2[2] = {0.f, 0.f};
    #pragma unroll 2
    for (int h4 = 0; h4 < HH / 4; ++h4) {
        const float4 w   = w24[h4];
        const float4 kb4 = kbTb[h4 * LK_ + j];
        const float4 ka4 = kaTb[h4 * LK_ + j];
        const int h = h4 * 4;
        #pragma unroll
        for (int r = 0; r < 2; ++r) {
            s1[r] = fmaf(fmaxf(qaR[r * HH + h + 0] + kb4.x, 0.f), w.x, s1[r]);
            s1[r] = fmaf(fmaxf(qaR[r * HH + h + 1] + kb4.y, 0.f), w.y, s1[r]);
            s1[r] = fmaf(fmaxf(qaR[r * HH + h + 2] + kb4.z, 0.f), w.z, s1[r]);
            s1[r] = fmaf(fmaxf(qaR[r * HH + h + 3] + kb4.w, 0.f), w.w, s1[r]);
            s2[r] = fmaf(fmaxf(qbR[r * HH + h + 0] + ka4.x, 0.f), w.x, s2[r]);
            s2[r] = fmaf(fmaxf(qbR[r * HH + h + 1] + ka4.y, 0.f), w.y, s2[r]);
            s2[r] = fmaf(fmaxf(qbR[r * HH + h + 2] + ka4.z, 0.f), w.z, s2[r]);
            s2[r] = fmaf(fmaxf(qbR[r * HH + h + 3] + ka4.w, 0.f), w.w, s2[r]);
        }
    }

    const float b2v = b2[0];
    float sv[2];
    #pragma unroll
    for (int r = 0; r < 2; ++r)
        sv[r] = s1[r] + s2[r] + 2.f * b2v + mk[r] * (-1e9f);

    // ---- softmax: row (row0+2rp+r) spans waves 8rp..8rp+7, one j/thread ----
    #pragma unroll
    for (int r = 0; r < 2; ++r) {
        float mv = sv[r];
        #pragma unroll
        for (int off = 32; off > 0; off >>= 1) mv = fmaxf(mv, __shfl_xor(mv, off));
        if (lane == 0) redm[wid][r] = mv;
    }
    __syncthreads();
    float m[2];
    #pragma unroll
    for (int r = 0; r < 2; ++r) {
        const int g = 8 * rp;
        float mv = redm[g][r];
        #pragma unroll
        for (int w = 1; w < 8; ++w) mv = fmaxf(mv, redm[g + w][r]);
        m[r] = mv;
    }

    float e[2];
    #pragma unroll
    for (int r = 0; r < 2; ++r) {
        e[r] = expf(sv[r] - m[r]);
        float s = e[r];
        #pragma unroll
        for (int off = 32; off > 0; off >>= 1) s += __shfl_xor(s, off);
        if (lane == 0) reds[wid][r] = s;
    }
    __syncthreads();

    float pv[2];
    #pragma unroll
    for (int r = 0; r < 2; ++r) {
        const int g = 8 * rp;
        float s = reds[g][r];
        #pragma unroll
        for (int w = 1; w < 8; ++w) s += reds[g + w][r];
        pv[r] = e[r] / s;
        attn[(row0 + 2 * rp + r) * LK_ + j] = pv[r];
    }
    // p_int[j][rlocal]; thread writes rlocal {2rp, 2rp+1} for its single j
    *reinterpret_cast<float2*>(&p_int[j * QR + 2 * rp]) =
        make_float2(pv[0], pv[1]);
    __syncthreads();

    // ---- PV: wave wid handles j in [wid*32, wid*32+32), lane = d ----
    float acc[QR] = {0.f, 0.f, 0.f, 0.f};
    {
        const int jb = wid * 32;
        const float* vb = vpd + (b * LK_ + jb) * DD;
        #pragma unroll 8
        for (int jj = 0; jj < 32; ++jj) {
            const float4 pj = *reinterpret_cast<const float4*>(&p_int[(jb + jj) * QR]);
            const float vv = vb[jj * DD + lane];
            acc[0] = fmaf(pj.x, vv, acc[0]);
            acc[1] = fmaf(pj.y, vv, acc[1]);
            acc[2] = fmaf(pj.z, vv, acc[2]);
            acc[3] = fmaf(pj.w, vv, acc[3]);
        }
    }
    #pragma unroll
    for (int r = 0; r < QR; ++r) opart[wid][r][lane] = acc[r];
    __syncthreads();

    // ---- combine 16 wave partials + bias -> out ----
    if (t < QR * DD) {
        const int r = t >> 6, d = t & 63;
        float o = opart[0][r][d];
        #pragma unroll
        for (int w = 1; w < 16; ++w) o += opart[w][r][d];
        out[(row0 + r) * DD + d] = o + db[d];
    }
}

extern "C" void kernel_launch(void* const* d_in, const int* in_sizes, int n_in,
                              void* d_out, int out_size, void* d_ws, size_t ws_size,
                              hipStream_t stream)
{
    const float* q    = (const float*)d_in[0];
    const float* k    = (const float*)d_in[1];
    const float* v    = (const float*)d_in[2];
    const float* mask = (const float*)d_in[3];
    const float* Ww   = (const float*)d_in[4];
    const float* wb   = (const float*)d_in[5];
    const float* Wd   = (const float*)d_in[6];
    const float* db   = (const float*)d_in[7];
    const float* W1   = (const float*)d_in[8];
    const float* b1   = (const float*)d_in[9];
    const float* W2   = (const float*)d_in[10];
    const float* b2   = (const float*)d_in[11];

    float* ws = (float*)d_ws;
    float* vpd = ws;                    // 1024*64   (= (v@Ww+wb)@Wd)
    float* qa  = vpd + NROWS * DD;      // 1024*128
    float* qb  = qa + NROWS * HH;
    float* kaTf = qb + NROWS * HH;      // 2*32*512*4 floats = 512 KB
    float* kbTf = kaTf + NROWS * HH;
    // total ws use ≈ 2.3 MB

    float* out  = (float*)d_out;        // 2*1*512*64
    float* attn = out + NROWS * DD;     // 2*1*512*512

    proj_kernel<<<dim3(3072), dim3(128), 0, stream>>>(
        q, k, v, Ww, wb, W1, b1, Wd, vpd, qa, qb, kaTf, kbTf);

    attn_kernel<<<dim3(NROWS / QR), dim3(1024), 0, stream>>>(
        mask, vpd, qa, qb, (const float4*)kaTf, (const float4*)kbTf,
        W2, b2, db, out, attn);
}

// Round 16
// 101.500 us; speedup vs baseline: 1.0992x; 1.0992x over previous
//
#include <hip/hip_runtime.h>
#include <hip/hip_bf16.h>

// Problem constants: B=2, H=1, LQ=LK=512, D=64, HID=128
// rows (B*H*L) = 1024 for q/k/v each.

#define NROWS 1024   // B*H*LQ
#define DD    64
#define HH    128
#define LK_   512
#define QR    4      // query rows per attn block

// ---------------------------------------------------------------------------
// Kernel A: projections + direct transposed k-table emit (trans fused away).
// grid = 3072 blocks (0..1023 q-rows, 1024..2047 k-rows, 2048..3071 v-rows),
// block = 128 threads.
//   all rows : xp = x @ Ww + wb   (only v rows store it, as vp)
//   q rows   : qa' = xp@W1q + b1 , qb' = xp@W1k + b1   (row-major [row][h])
//   k rows   : kaT[b][h/4][j][h%4] = xp@W1q ; kbT likewise (transposed emit)
// ---------------------------------------------------------------------------
__global__ __launch_bounds__(128)
void proj_kernel(const float* __restrict__ q, const float* __restrict__ k,
                 const float* __restrict__ v,
                 const float* __restrict__ Ww, const float* __restrict__ wb,
                 const float* __restrict__ W1, const float* __restrict__ b1,
                 float* __restrict__ vp,
                 float* __restrict__ qa, float* __restrict__ qb,
                 float* __restrict__ kaTf, float* __restrict__ kbTf)
{
    const int r    = blockIdx.x;
    const int type = r >> 10;      // 0=q,1=k,2=v
    const int idx  = r & 1023;
    const int t    = threadIdx.x;  // 0..127

    const float* src = (type == 0) ? q : (type == 1) ? k : v;

    __shared__ float x[DD];
    __shared__ float xp[DD];

    if (t < DD) x[t] = src[idx * DD + t];
    __syncthreads();

    if (t < DD) {
        float acc = wb[t];
        #pragma unroll
        for (int c = 0; c < DD; ++c) acc = fmaf(x[c], Ww[c * DD + t], acc);
        xp[t] = acc;
        if (type == 2) vp[idx * DD + t] = acc;   // only v needs the projection
    }
    __syncthreads();

    if (type == 2) return;

    // thread t = output column h of the HID=128 projections
    float accA = 0.f;   // xp @ W1q  (W1 rows 0..63)
    float accB = 0.f;   // xp @ W1k  (W1 rows 64..127)
    #pragma unroll
    for (int d = 0; d < DD; ++d) {
        const float xv = xp[d];
        accA = fmaf(xv, W1[d * HH + t],        accA);
        accB = fmaf(xv, W1[(DD + d) * HH + t], accB);
    }
    if (type == 0) {
        qa[idx * HH + t] = accA + b1[t];
        qb[idx * HH + t] = accB + b1[t];
    } else {
        // transposed emit: h-chunked float4 layout [b][h4][j][c]
        const int b  = idx >> 9;
        const int j  = idx & (LK_ - 1);
        const int o  = ((b * (HH / 4) + (t >> 2)) * LK_ + j) * 4 + (t & 3);
        kaTf[o] = accA;
        kbTf[o] = accB;
    }
}

// ---------------------------------------------------------------------------
// Kernel B: fused logits + softmax + PV + output projection.
// grid = 256 blocks (QR=4 q-rows), block = 512 threads (8 waves), thread = j.
// Hot loop per 4h: 2 coalesced k-side dwordx4 + 1 W2 dwordx4 (uniform->SMEM)
//                  + 16 scalar q-side uniform loads (SMEM pipe) + 96 VALU.
// Unroll capped at 2 to bound VGPR pressure (round-7 lesson).
// ---------------------------------------------------------------------------
__global__ __launch_bounds__(512)
void attn_kernel(const float* __restrict__ mask,
                 const float* __restrict__ vp,
                 const float* __restrict__ qa, const float* __restrict__ qb,
                 const float4* __restrict__ kaT, const float4* __restrict__ kbT,
                 const float* __restrict__ W2, const float* __restrict__ b2,
                 const float* __restrict__ Wd, const float* __restrict__ db,
                 float* __restrict__ out, float* __restrict__ attn)
{
    const int row0 = blockIdx.x * QR;   // first of 4 query rows (4 | 512)
    const int b    = row0 >> 9;
    const int t    = threadIdx.x;       // 0..511 == key column j
    const int wid  = t >> 6;            // wave 0..7
    const int lane = t & 63;
    const int j    = t;

    __shared__ float p_int[LK_ * QR];   // p interleaved [j][r] -> b128 broadcast in PV
    __shared__ float redm[8][QR];
    __shared__ float reds[8][QR];
    __shared__ float opart[8][QR][DD];
    __shared__ float o_l[QR][DD];

    const float4* kaTb = kaT + b * (HH / 4) * LK_;
    const float4* kbTb = kbT + b * (HH / 4) * LK_;
    const float*  qaR  = qa + row0 * HH;   // wave-uniform base -> s_load
    const float*  qbR  = qb + row0 * HH;
    const float4* w24  = reinterpret_cast<const float4*>(W2);

    // prefetch mask early (overlaps hot loop)
    float mk[QR];
    #pragma unroll
    for (int r = 0; r < QR; ++r) mk[r] = mask[(row0 + r) * LK_ + j];

    // ---- logits: 4 rows x (2 relu-dot terms over HID=128), 4 h per iter ----
    float s1[QR] = {0.f, 0.f, 0.f, 0.f};
    float s2[QR] = {0.f, 0.f, 0.f, 0.f};
    #pragma unroll 2
    for (int h4 = 0; h4 < HH / 4; ++h4) {
        const float4 w   = w24[h4];
        const float4 kb4 = kbTb[h4 * LK_ + j];
        const float4 ka4 = kaTb[h4 * LK_ + j];
        const int h = h4 * 4;
        #pragma unroll
        for (int r = 0; r < QR; ++r) {
            s1[r] = fmaf(fmaxf(qaR[r * HH + h + 0] + kb4.x, 0.f), w.x, s1[r]);
            s1[r] = fmaf(fmaxf(qaR[r * HH + h + 1] + kb4.y, 0.f), w.y, s1[r]);
            s1[r] = fmaf(fmaxf(qaR[r * HH + h + 2] + kb4.z, 0.f), w.z, s1[r]);
            s1[r] = fmaf(fmaxf(qaR[r * HH + h + 3] + kb4.w, 0.f), w.w, s1[r]);
            s2[r] = fmaf(fmaxf(qbR[r * HH + h + 0] + ka4.x, 0.f), w.x, s2[r]);
            s2[r] = fmaf(fmaxf(qbR[r * HH + h + 1] + ka4.y, 0.f), w.y, s2[r]);
            s2[r] = fmaf(fmaxf(qbR[r * HH + h + 2] + ka4.z, 0.f), w.z, s2[r]);
            s2[r] = fmaf(fmaxf(qbR[r * HH + h + 3] + ka4.w, 0.f), w.w, s2[r]);
        }
    }

    const float b2v = b2[0];
    float sv[QR];
    #pragma unroll
    for (int r = 0; r < QR; ++r)
        sv[r] = s1[r] + s2[r] + 2.f * b2v + mk[r] * (-1e9f);

    // ---- softmax per row over 512 logits (one per thread) ----
    float m[QR];
    #pragma unroll
    for (int r = 0; r < QR; ++r) {
        float mv = sv[r];
        #pragma unroll
        for (int off = 32; off > 0; off >>= 1) mv = fmaxf(mv, __shfl_xor(mv, off));
        if (lane == 0) redm[wid][r] = mv;
    }
    __syncthreads();
    #pragma unroll
    for (int r = 0; r < QR; ++r) {
        float mv = redm[0][r];
        #pragma unroll
        for (int w = 1; w < 8; ++w) mv = fmaxf(mv, redm[w][r]);
        m[r] = mv;
    }

    float e[QR];
    #pragma unroll
    for (int r = 0; r < QR; ++r) {
        e[r] = expf(sv[r] - m[r]);
        float s = e[r];
        #pragma unroll
        for (int off = 32; off > 0; off >>= 1) s += __shfl_xor(s, off);
        if (lane == 0) reds[wid][r] = s;
    }
    __syncthreads();

    float pv[QR];
    #pragma unroll
    for (int r = 0; r < QR; ++r) {
        float s = reds[0][r];
        #pragma unroll
        for (int w = 1; w < 8; ++w) s += reds[w][r];
        pv[r] = e[r] / s;
        attn[(row0 + r) * LK_ + j] = pv[r];
    }
    // interleaved p: one b128 store; PV reads one b128 broadcast per j
    *reinterpret_cast<float4*>(&p_int[j * QR]) =
        make_float4(pv[0], pv[1], pv[2], pv[3]);
    __syncthreads();

    // ---- PV: wave wid handles j in [wid*64, wid*64+64), lane = d ----
    float acc[QR] = {0.f, 0.f, 0.f, 0.f};
    {
        const int jb = wid * 64;
        const float* vpb = vp + (b * LK_ + jb) * DD;
        #pragma unroll 8
        for (int jj = 0; jj < 64; ++jj) {
            const float4 pj = *reinterpret_cast<const float4*>(&p_int[(jb + jj) * QR]);
            const float vv = vpb[jj * DD + lane];
            acc[0] = fmaf(pj.x, vv, acc[0]);
            acc[1] = fmaf(pj.y, vv, acc[1]);
            acc[2] = fmaf(pj.z, vv, acc[2]);
            acc[3] = fmaf(pj.w, vv, acc[3]);
        }
    }
    #pragma unroll
    for (int r = 0; r < QR; ++r) opart[wid][r][lane] = acc[r];
    __syncthreads();

    // ---- combine 8 wave partials -> o_l ----
    if (t < QR * DD) {
        const int r = t >> 6, d = t & 63;
        float o = opart[0][r][d];
        #pragma unroll
        for (int w = 1; w < 8; ++w) o += opart[w][r][d];
        o_l[r][d] = o;
    }
    __syncthreads();

    // ---- final: out = o @ Wd + db ----
    if (t < QR * DD) {
        const int r = t >> 6, d = t & 63;
        float res = db[d];
        #pragma unroll
        for (int c = 0; c < DD; ++c) res = fmaf(o_l[r][c], Wd[c * DD + d], res);
        out[(row0 + r) * DD + d] = res;
    }
}

extern "C" void kernel_launch(void* const* d_in, const int* in_sizes, int n_in,
                              void* d_out, int out_size, void* d_ws, size_t ws_size,
                              hipStream_t stream)
{
    const float* q    = (const float*)d_in[0];
    const float* k    = (const float*)d_in[1];
    const float* v    = (const float*)d_in[2];
    const float* mask = (const float*)d_in[3];
    const float* Ww   = (const float*)d_in[4];
    const float* wb   = (const float*)d_in[5];
    const float* Wd   = (const float*)d_in[6];
    const float* db   = (const float*)d_in[7];
    const float* W1   = (const float*)d_in[8];
    const float* b1   = (const float*)d_in[9];
    const float* W2   = (const float*)d_in[10];
    const float* b2   = (const float*)d_in[11];

    float* ws = (float*)d_ws;
    float* vp = ws;                    // 1024*64
    float* qa = vp + NROWS * DD;       // 1024*128
    float* qb = qa + NROWS * HH;
    float* kaTf = qb + NROWS * HH;     // 2*32*512*4 floats = 512 KB
    float* kbTf = kaTf + NROWS * HH;
    // total ws use ≈ 2.3 MB

    float* out  = (float*)d_out;        // 2*1*512*64
    float* attn = out + NROWS * DD;     // 2*1*512*512

    proj_kernel<<<dim3(3072), dim3(128), 0, stream>>>(
        q, k, v, Ww, wb, W1, b1, vp, qa, qb, kaTf, kbTf);

    attn_kernel<<<dim3(NROWS / QR), dim3(512), 0, stream>>>(
        mask, vp, qa, qb, (const float4*)kaTf, (const float4*)kbTf,
        W2, b2, Wd, db, out, attn);
}